// Round 3
// baseline (4455.455 us; speedup 1.0000x reference)
//
#include <hip/hip_runtime.h>

// RecurrentGaussianActor: fused LSTM(64->256) + Linear+ReLU(256) + 2 heads(16).
// One WG per batch row (256 WGs x 512 threads), persistent over T=1000 steps.
// Round-3 structure: thread (half,j) computes the FOUR gate rows of unit j
// (j, j+256, j+512, j+768) over K-half `half` (64 h-pairs). h-broadcast LDS
// reads drop 32->16 b128/thread (each feeds 4 rows), and the gate exchange is
// one contiguous float4 per unit (no gbuf round trip): thread (0,j) owns c[j]
// and fuses partial-combine + elementwise. W_hh: 192 pairs/thread in AGPRs
// (volatile loads - round-2-proven resident), 64 pairs via LDS.

#define NB 256
#define NT 1000
#define NF 64
#define NH 256
#define NG 1024
#define NA 16
#define NTHREADS 512
#define CHUNK 8
#define NCHUNK (NT / CHUNK)

typedef _Float16 h2 __attribute__((ext_vector_type(2)));
typedef _Float16 h8 __attribute__((ext_vector_type(8)));
typedef float f4 __attribute__((ext_vector_type(4)));

__device__ __forceinline__ float fdot2(h2 a, h2 b, float c) {
  return __builtin_amdgcn_fdot2(a, b, c, false);
}
__device__ __forceinline__ float fexp2(float x) { return __builtin_amdgcn_exp2f(x); }
__device__ __forceinline__ float frcp(float x) { return __builtin_amdgcn_rcpf(x); }
__device__ __forceinline__ float sigmoidf_(float x) {
  return frcp(1.f + fexp2(-1.4426950408889634f * x));
}
__device__ __forceinline__ float tanhfast(float x) {
  float a = fabsf(x);
  float e = fexp2(-2.8853900817779268f * a);
  float r = (1.f - e) * frcp(1.f + e);
  return __builtin_copysignf(r, x);
}
__device__ __forceinline__ float dot8(h8 x, h8 w, float acc) {
  acc = fdot2(__builtin_shufflevector(x, x, 0, 1), __builtin_shufflevector(w, w, 0, 1), acc);
  acc = fdot2(__builtin_shufflevector(x, x, 2, 3), __builtin_shufflevector(w, w, 2, 3), acc);
  acc = fdot2(__builtin_shufflevector(x, x, 4, 5), __builtin_shufflevector(w, w, 4, 5), acc);
  acc = fdot2(__builtin_shufflevector(x, x, 6, 7), __builtin_shufflevector(w, w, 6, 7), acc);
  return acc;
}

// ---- prep: convert/pack weights to f16 pairs in workspace ----
__global__ void prep_kernel(const float* __restrict__ Wih, const float* __restrict__ Whh,
                            const float* __restrict__ bih, const float* __restrict__ bhh,
                            const float* __restrict__ W2, const float* __restrict__ Wm,
                            const float* __restrict__ Ws,
                            h2* __restrict__ whh, h2* __restrict__ wih,
                            h2* __restrict__ w2w, h2* __restrict__ wmh,
                            float* __restrict__ bg) {
  int i = blockIdx.x * 256 + threadIdx.x;
  if (i < 1024 * 128) {  // W_hh [1024][256] -> [1024][128] pairs
    int j = i >> 7, p = i & 127;
    whh[i] = h2{(_Float16)Whh[j * 256 + 2 * p], (_Float16)Whh[j * 256 + 2 * p + 1]};
  }
  if (i < 1024 * 32) {   // W_ih [1024][64] -> [1024][32] pairs
    int j = i >> 5, p = i & 31;
    wih[i] = h2{(_Float16)Wih[j * 64 + 2 * p], (_Float16)Wih[j * 64 + 2 * p + 1]};
  }
  if (i < 256 * 128) {   // W2 [256][256] -> [256][128] pairs
    int j = i >> 7, p = i & 127;
    w2w[i] = h2{(_Float16)W2[j * 256 + 2 * p], (_Float16)W2[j * 256 + 2 * p + 1]};
  }
  if (i < 32 * 128) {    // Wm rows 0..15, Ws rows 16..31
    int j = i >> 7, p = i & 127;
    float v0, v1;
    if (j < 16) { v0 = Wm[j * 256 + 2 * p]; v1 = Wm[j * 256 + 2 * p + 1]; }
    else        { v0 = Ws[(j - 16) * 256 + 2 * p]; v1 = Ws[(j - 16) * 256 + 2 * p + 1]; }
    wmh[i] = h2{(_Float16)v0, (_Float16)v1};
  }
  if (i < 1024) bg[i] = bih[i] + bhh[i];
}

// ---- main fused persistent kernel: 1 WG per batch row ----
__global__ __launch_bounds__(NTHREADS, 2) void actor_kernel(
    const float* __restrict__ obs,
    const h2* __restrict__ whh, const h2* __restrict__ wih,
    const h2* __restrict__ w2w, const h2* __restrict__ wmh,
    const float* __restrict__ bg, const float* __restrict__ b2,
    const float* __restrict__ bm, const float* __restrict__ bs,
    float* __restrict__ out) {
  // whh_l[q*1024+row], q = serving_half*4 + p4: pairs [64*sh + 4*p4, +4) of row
  __shared__ __align__(16) h8 whh_l[8 * 1024];         // 131072 B
  __shared__ __align__(16) _Float16 xg_l[CHUNK * NG];  // 16384 B, [t][row]
  __shared__ __align__(16) f4 pbuf[NH];                // 4096 B  partial gates (half 1)
  __shared__ __align__(16) h2 hbuf[NH / 2];            // 512 B   current h
  __shared__ __align__(16) h2 hch[CHUNK * NH / 2];     // 4096 B  h history
  __shared__ __align__(16) h2 xbuf[CHUNK * NF / 2];    // 1024 B  obs chunk
  __shared__ __align__(16) h2 x2b[CHUNK * NH / 2];     // 4096 B  layer2 out
  // total 161280 B <= 163840

  const int tid = threadIdx.x;
  const int b = blockIdx.x;
  const int half = tid >> 8;   // K-half this thread covers
  const int j = tid & 255;     // unit index (4 gate rows j+256g)

  // ---- register/AGPR-resident W_hh: rows j+256g, h8-groups [16h+4, 16h+16) ----
  h8 wreg[48];  // [g*12 + m]
  {
    const volatile h8* vw = (const volatile h8*)whh;  // row stride = 32 h8
#pragma unroll
    for (int g = 0; g < 4; g++)
#pragma unroll
      for (int m = 0; m < 12; m++)
        wreg[g * 12 + m] = vw[(g * 256 + j) * 32 + half * 16 + 4 + m];
  }
  // ---- LDS-resident W_hh: h8-groups [16h, 16h+4) of every row ----
  {
    const h8* whh8 = (const h8*)whh;
    for (int k = tid; k < 8 * 1024; k += NTHREADS) {
      int q = k >> 10, row = k & 1023;
      whh_l[q * 1024 + row] = whh8[row * 32 + (q >> 2) * 16 + (q & 3)];
    }
  }
  if (tid < NH / 2) hbuf[tid] = h2{(_Float16)0.f, (_Float16)0.f};
  float c_state = 0.f;  // owned by half==0 thread j
  const int r0 = tid, r1 = tid + NTHREADS;  // rows for the xg chunk phase
  const float biasg0 = bg[r0], biasg1 = bg[r1];
  const float b2v = b2[tid & 255];
  const int oh = tid & 31;
  const float hbv = (oh < NA) ? bm[oh] : bs[oh - NA];
  __syncthreads();

  const float* obs_b = obs + (size_t)b * NT * NF;
  float* out_means = out;
  float* out_stds = out + (size_t)NB * NT * NA;

  for (int ch = 0; ch < NCHUNK; ++ch) {
    const int t0 = ch * CHUNK;

    // ---- stage obs chunk -> f16 pairs in LDS ----
    if (tid < 128) {
      int t = tid >> 4, fq = tid & 15;
      f4 v = *(const f4*)(obs_b + (size_t)(t0 + t) * NF + fq * 4);
      xbuf[t * 32 + fq * 2] = h2{(_Float16)v[0], (_Float16)v[1]};
      xbuf[t * 32 + fq * 2 + 1] = h2{(_Float16)v[2], (_Float16)v[3]};
    }
    __syncthreads();

    // ---- xg = obs @ W_ih^T + (b_ih+b_hh) for the chunk ----
#pragma unroll
    for (int rr = 0; rr < 2; ++rr) {
      const int row = rr ? r1 : r0;
      const float bias = rr ? biasg1 : biasg0;
      float acc[CHUNK];
#pragma unroll
      for (int t = 0; t < CHUNK; t++) acc[t] = bias;
      const h8* wrow = (const h8*)wih + row * 8;
#pragma unroll
      for (int jh = 0; jh < 2; jh++) {
        h8 w[4];
#pragma unroll
        for (int q = 0; q < 4; q++) w[q] = wrow[jh * 4 + q];
#pragma unroll
        for (int t = 0; t < CHUNK; t++) {
#pragma unroll
          for (int q = 0; q < 4; q++) {
            h8 xv = *(const h8*)&xbuf[t * 32 + jh * 16 + q * 4];
            acc[t] = dot8(xv, w[q], acc[t]);
          }
        }
      }
#pragma unroll
      for (int t = 0; t < CHUNK; t++) xg_l[t * NG + row] = (_Float16)acc[t];
    }
    __syncthreads();

    // ---- 8 recurrent LSTM steps ----
    for (int t = 0; t < CHUNK; t++) {
      float a0 = 0.f, a1 = 0.f, a2 = 0.f, a3 = 0.f;
      // LDS weight part: h8-groups [16h, 16h+4)
#pragma unroll
      for (int p4 = 0; p4 < 4; p4++) {
        h8 hv = *(const h8*)&hbuf[half * 64 + p4 * 4];  // wave-uniform broadcast
        const h8* wl = &whh_l[(half * 4 + p4) * 1024 + j];
        a0 = dot8(hv, wl[0], a0);
        a1 = dot8(hv, wl[256], a1);
        a2 = dot8(hv, wl[512], a2);
        a3 = dot8(hv, wl[768], a3);
      }
      // register/AGPR weight part: h8-groups [16h+4, 16h+16)
#pragma unroll
      for (int m = 0; m < 12; m++) {
        h8 hv = *(const h8*)&hbuf[half * 64 + 16 + 4 * m];
        a0 = dot8(hv, wreg[m], a0);
        a1 = dot8(hv, wreg[12 + m], a1);
        a2 = dot8(hv, wreg[24 + m], a2);
        a3 = dot8(hv, wreg[36 + m], a3);
      }
      if (half) pbuf[j] = f4{a0, a1, a2, a3};
      __syncthreads();
      if (!half) {
        f4 o4 = pbuf[j];
        float gi = a0 + o4.x + (float)xg_l[t * NG + j];
        float gf = a1 + o4.y + (float)xg_l[t * NG + 256 + j];
        float gg = a2 + o4.z + (float)xg_l[t * NG + 512 + j];
        float go = a3 + o4.w + (float)xg_l[t * NG + 768 + j];
        gi = sigmoidf_(gi);
        gf = sigmoidf_(gf);
        gg = tanhfast(gg);
        go = sigmoidf_(go);
        c_state = gf * c_state + gi * gg;
        float hval = go * tanhfast(c_state);
        _Float16 hh = (_Float16)hval;
        ((_Float16*)hbuf)[j] = hh;
        ((_Float16*)hch)[t * NH + j] = hh;
      }
      __syncthreads();
    }

    // ---- layer2: x2 = relu(h @ W2^T + b2) ----
    {
      const int o = tid & 255;
      const int tb = (tid >> 8) * 4;  // 4 timesteps per thread
      float acc[4] = {b2v, b2v, b2v, b2v};
      const h8* wrow = (const h8*)w2w + o * 32;
#pragma unroll 2
      for (int c = 0; c < 8; c++) {
        h8 w[4];
#pragma unroll
        for (int q = 0; q < 4; q++) w[q] = wrow[c * 4 + q];
#pragma unroll
        for (int tt = 0; tt < 4; tt++) {
#pragma unroll
          for (int q = 0; q < 4; q++) {
            h8 xv = *(const h8*)&hch[(tb + tt) * 128 + c * 16 + q * 4];
            acc[tt] = dot8(xv, w[q], acc[tt]);
          }
        }
      }
#pragma unroll
      for (int tt = 0; tt < 4; tt++)
        ((_Float16*)x2b)[(tb + tt) * NH + o] = (_Float16)fmaxf(acc[tt], 0.f);
    }
    __syncthreads();

    // ---- heads: 32 outputs x 8 timesteps on first 256 threads ----
    if (tid < 256) {
      const int tt = tid >> 5;
      const h8* wrow = (const h8*)wmh + oh * 32;
      float acc = 0.f;
#pragma unroll 4
      for (int c = 0; c < 32; c++) {
        h8 xv = *(const h8*)&x2b[tt * 128 + c * 4];
        acc = dot8(xv, wrow[c], acc);
      }
      acc += hbv;
      const size_t idx = ((size_t)b * NT + (t0 + tt)) * NA + (oh & 15);
      if (oh < NA) {
        out_means[idx] = acc;
      } else {
        float ls = fminf(fmaxf(acc, -20.f), 2.f);
        out_stds[idx] = fexp2(1.4426950408889634f * ls);
      }
    }
    // next writes to x2b/xbuf are separated from these reads by the next
    // chunk's staging/step barriers.
  }
}

extern "C" void kernel_launch(void* const* d_in, const int* in_sizes, int n_in,
                              void* d_out, int out_size, void* d_ws, size_t ws_size,
                              hipStream_t stream) {
  const float* obs = (const float*)d_in[0];
  const float* Wih = (const float*)d_in[1];
  const float* Whh = (const float*)d_in[2];
  const float* bih = (const float*)d_in[3];
  const float* bhh = (const float*)d_in[4];
  const float* W2 = (const float*)d_in[5];
  const float* b2 = (const float*)d_in[6];
  const float* Wm = (const float*)d_in[7];
  const float* bm = (const float*)d_in[8];
  const float* Ws = (const float*)d_in[9];
  const float* bs = (const float*)d_in[10];

  char* ws = (char*)d_ws;
  h2* whh = (h2*)(ws + 0);            // 512 KB
  h2* wih = (h2*)(ws + 524288);       // 128 KB
  h2* w2w = (h2*)(ws + 655360);       // 128 KB
  h2* wmh = (h2*)(ws + 786432);       // 16 KB
  float* bg = (float*)(ws + 802816);  // 4 KB

  prep_kernel<<<512, 256, 0, stream>>>(Wih, Whh, bih, bhh, W2, Wm, Ws,
                                       whh, wih, w2w, wmh, bg);
  actor_kernel<<<NB, NTHREADS, 0, stream>>>(obs, whh, wih, w2w, wmh, bg, b2, bm,
                                            bs, (float*)d_out);
}